// Round 9
// baseline (3227.305 us; speedup 1.0000x reference)
//
#include <hip/hip_runtime.h>

#define TT 512
#define BB 64
#define II 512
#define LL 1024
#define GROUPS 16
#define RPG 4            // batch rows per group
#define WPG 8            // WGs per group (128 cols each)
#define NWGS (GROUPS * WPG)

typedef __bf16 bf16x8 __attribute__((ext_vector_type(8)));
typedef float f32x4 __attribute__((ext_vector_type(4)));
typedef unsigned int u32x4 __attribute__((ext_vector_type(4)));

// ---------- workspace layout (bytes) ----------
// wsWi : Wi frag-ordered bf16 (xi_gemm)                          = 1 MiB
// wsWh2: Wh frag-ordered bf16 [8 w][8 wv][32 ks][64 l][8e]       = 2 MiB
// hbuf : ping-pong compact H  2 x [16 g][32 ks][4 kq][4 r][8e]   = 256 KiB
// flags: [16 g][64] uints — one per producer WAVE (w*8+wv)       = 4 KiB
#define WSWI_OFF 0u
#define WSWH_OFF (1u << 20)
#define HBUF_OFF (3u << 20)
#define FLAG_OFF ((3u << 20) + (1u << 18))

__device__ __forceinline__ unsigned short f2bf(float f) {
  unsigned int u = __builtin_bit_cast(unsigned int, f);
  u += 0x7fffu + ((u >> 16) & 1u);   // round-to-nearest-even (inputs finite)
  return (unsigned short)(u >> 16);
}

__device__ __forceinline__ bf16x8 ld_frag(const unsigned short* p) {
  return __builtin_bit_cast(bf16x8, *(const uint4*)p);
}

// ============================================================
// prep: frag-order Wi (xi_gemm), Wh2 (scan), compact h0; zero flags.
// ============================================================
__global__ __launch_bounds__(256) void prep_kernel(
    const float* __restrict__ h0, const float* __restrict__ Wi,
    const float* __restrict__ Wh, unsigned short* __restrict__ wsWi,
    unsigned short* __restrict__ wsWh2, unsigned short* __restrict__ hbuf,
    unsigned int* __restrict__ flags) {
  int idx = blockIdx.x * 256 + threadIdx.x;
  if (idx < GROUPS * 64) flags[idx] = 0u;
  const float* src;
  unsigned short* dst;
  if (idx < 65536) {                       // Wi slots (for xi_gemm)
    int ln = idx & 63, s = idx >> 6;
    int nsub = s & 7, s2 = s >> 3, ks = s2 & 15, bn = s2 >> 4;
    int n = bn * 128 + nsub * 16 + (ln & 15);
    int k = ks * 32 + (ln >> 4) * 8;
    src = Wi + (size_t)n * II + k;
    dst = wsWi + (size_t)idx * 8;
  } else if (idx < 196608) {               // Wh2 slots [w:8][wv:8][ks:32][l:64]
    int o = idx - 65536;
    int l = o & 63, s = o >> 6;
    int ks = s & 31, s2 = s >> 5;
    int wvp = s2 & 7, wp = s2 >> 3;
    int col = wp * 128 + wvp * 16 + (l & 15);
    int k = ks * 32 + (l >> 4) * 8;
    src = Wh + (size_t)col * LL + k;
    dst = wsWh2 + (size_t)o * 8;
  } else if (idx < 204800) {               // h0 compact slots [g][ks][kq][r][8e]
    int o = idx - 196608;
    int r = o & 3, kq = (o >> 2) & 3, ks = (o >> 4) & 31, g = o >> 9;
    src = h0 + (size_t)(g * RPG + r) * LL + ks * 32 + kq * 8;
    dst = hbuf + (size_t)o * 8;
  } else {
    return;
  }
  float4 a0 = *(const float4*)src;
  float4 a1 = *(const float4*)(src + 4);
  uint4 p;
  p.x = f2bf(a0.x) | ((unsigned)f2bf(a0.y) << 16);
  p.y = f2bf(a0.z) | ((unsigned)f2bf(a0.w) << 16);
  p.z = f2bf(a1.x) | ((unsigned)f2bf(a1.y) << 16);
  p.w = f2bf(a1.z) | ((unsigned)f2bf(a1.w) << 16);
  *(uint4*)dst = p;
}

// ============================================================
// xi = x @ Wi^T + bi  -> d_out (reused as xi buffer) [unchanged]
// ============================================================
__global__ __launch_bounds__(256) void xi_gemm(
    const float* __restrict__ x, const float* __restrict__ bi,
    const unsigned short* __restrict__ wsWi, float* __restrict__ out) {
  __shared__ unsigned short As[8 * 64 * 8];
  __shared__ unsigned short Bs[8 * 64 * 8];
  const int tid = threadIdx.x;
  const int ln = tid & 63;
  const int wv = tid >> 6;
  const int wm = wv >> 1, wn = wv & 1;
  const int bn = blockIdx.x;
  const int Mbase = blockIdx.y * 128;
  const int Nbase = bn * 128;

  f32x4 acc[4][4] = {};

  for (int ks = 0; ks < 16; ++ks) {
    __syncthreads();
#pragma unroll
    for (int i = 0; i < 2; ++i) {
      int slot = tid + 256 * i;
      int msub = slot >> 6;
      int l2 = slot & 63;
      const float* src =
          x + (size_t)(Mbase + msub * 16 + (l2 & 15)) * II + ks * 32 + (l2 >> 4) * 8;
      float4 a0 = *(const float4*)src;
      float4 a1 = *(const float4*)(src + 4);
      uint4 p;
      p.x = f2bf(a0.x) | ((unsigned)f2bf(a0.y) << 16);
      p.y = f2bf(a0.z) | ((unsigned)f2bf(a0.w) << 16);
      p.z = f2bf(a1.x) | ((unsigned)f2bf(a1.y) << 16);
      p.w = f2bf(a1.z) | ((unsigned)f2bf(a1.w) << 16);
      *(uint4*)(As + slot * 8) = p;
      const uint4* bsrc = (const uint4*)(wsWi + (size_t)(bn * 16 + ks) * 4096) + slot;
      *(uint4*)(Bs + slot * 8) = *bsrc;
    }
    __syncthreads();
    bf16x8 af[4];
#pragma unroll
    for (int m = 0; m < 4; ++m)
      af[m] = ld_frag(As + ((wm * 4 + m) * 64 + ln) * 8);
#pragma unroll
    for (int n = 0; n < 4; ++n) {
      bf16x8 bf = ld_frag(Bs + ((wn * 4 + n) * 64 + ln) * 8);
#pragma unroll
      for (int m = 0; m < 4; ++m)
        acc[m][n] = __builtin_amdgcn_mfma_f32_16x16x32_bf16(af[m], bf, acc[m][n], 0, 0, 0);
    }
  }
#pragma unroll
  for (int n = 0; n < 4; ++n) {
    int col = Nbase + wn * 64 + n * 16 + (ln & 15);
    float bv = bi[col];
#pragma unroll
    for (int m = 0; m < 4; ++m) {
      int row0 = Mbase + wm * 64 + m * 16 + (ln >> 4) * 4;
#pragma unroll
      for (int r = 0; r < 4; ++r)
        out[(size_t)(row0 + r) * LL + col] = acc[m][n][r] + bv;
    }
  }
}

// ============================================================
// Batch-grouped persistent scan v3.
// 16 groups x 4 rows; 8 WGs/group x 512 thr (8 waves x 16 cols).
// B pinned in 128 VGPRs via asm loads (remat-proof).
// Per step: poll 64 wave-flags -> one dwordx4/thread gather (8KB)
// -> LDS dbuf -> ONE barrier -> 32 MFMA (B in regs) -> tanh ->
// h-store (sc1) -> out-store -> vmcnt(1) -> per-wave flag.
// ============================================================
__global__ __launch_bounds__(512, 2) void scan_kernel(
    const unsigned short* __restrict__ wsWh2, float* __restrict__ out,
    unsigned short* __restrict__ hbuf, unsigned int* __restrict__ flags) {
  __shared__ unsigned short hA[2][4096];      // 2 x 8 KiB compact H
  __shared__ unsigned short packb[8][64];     // per-wave pack, 128 B each

  const int tid = threadIdx.x;
  const int ln = tid & 63;
  const int wv = tid >> 6;                 // 0..7 : 16-col subtile
  const int bid = blockIdx.x;
  const int g = ((bid & 7) << 1) | ((bid >> 3) & 1);  // group (XCD-clustered)
  const int w = bid >> 4;                  // 0..7 : 128-col slice
  const int kq = ln >> 4;                  // batch row this lane owns
  const int rdup = ln & 3;
  const int cc = ln & 15;                  // col within wave's 16
  const int ks_w = w * 4 + (wv >> 1);      // wave's compact-h ks slot
  const int half = wv & 1;

  // ---- B-frags pinned in VGPRs via asm loads (32 x 16B = 128 VGPR) ----
  u32x4 Breg[32];
  {
    const unsigned short* bsrc = wsWh2 + (size_t)(w * 8 + wv) * 16384 + ln * 8;
#pragma unroll
    for (int i = 0; i < 8; ++i) {
      const unsigned short* bp = bsrc + i * 2048;
      asm volatile(
          "global_load_dwordx4 %0, %4, off\n\t"
          "global_load_dwordx4 %1, %4, off offset:1024\n\t"
          "global_load_dwordx4 %2, %4, off offset:2048\n\t"
          "global_load_dwordx4 %3, %4, off offset:3072"
          : "=&v"(Breg[i * 4]), "=&v"(Breg[i * 4 + 1]),
            "=&v"(Breg[i * 4 + 2]), "=&v"(Breg[i * 4 + 3])
          : "v"(bp) : "memory");
    }
    asm volatile("s_waitcnt vmcnt(0)" ::: "memory");
  }

  const unsigned int* fp = flags + g * 64 + ln;   // all 64 producer-wave flags

  for (int t = 0; t < TT; ++t) {
    // ---- xi prefetch (plain cached; waited at gather vmcnt(0)) ----
    float xv;
    const float* xp = out + (size_t)t * 65536 + (size_t)(g * RPG + kq) * LL +
                      w * 128 + wv * 16 + cc;
    asm volatile("global_load_dword %0, %1, off" : "=&v"(xv) : "v"(xp) : "memory");

    // ---- wait-all: 64 producer waves published step t-1 ----
    if (t > 0) {
      unsigned f;
      do {
        f = __hip_atomic_load(fp, __ATOMIC_RELAXED, __HIP_MEMORY_SCOPE_AGENT);
      } while (__all((int)f >= t) == 0);
    }
    __builtin_amdgcn_sched_barrier(0);

    // ---- shared gather: 8 KB group state, one dwordx4 per thread ----
    const unsigned short* hcur = hbuf + (size_t)(t & 1) * 65536 + g * 4096;
    u32x4 hv0;
    asm volatile("global_load_dwordx4 %0, %1, off sc1"
                 : "=&v"(hv0) : "v"(hcur + tid * 8) : "memory");
    asm volatile("s_waitcnt vmcnt(0)" ::: "memory");
    __builtin_amdgcn_sched_barrier(0);
    unsigned short* hw = hA[t & 1];
    *(u32x4*)(hw + tid * 8) = hv0;
    __syncthreads();                       // the ONE block barrier per step

    // ---- MFMA: K=1024, A from LDS (broadcast), B in registers ----
    f32x4 a0 = {}, a1 = {};
#pragma unroll
    for (int ks = 0; ks < 32; ks += 2) {
      bf16x8 A0 = ld_frag(hw + (ks * 16 + kq * 4 + rdup) * 8);
      bf16x8 A1 = ld_frag(hw + ((ks + 1) * 16 + kq * 4 + rdup) * 8);
      a0 = __builtin_amdgcn_mfma_f32_16x16x32_bf16(
          A0, __builtin_bit_cast(bf16x8, Breg[ks]), a0, 0, 0, 0);
      a1 = __builtin_amdgcn_mfma_f32_16x16x32_bf16(
          A1, __builtin_bit_cast(bf16x8, Breg[ks + 1]), a1, 0, 0, 0);
    }
    f32x4 s = a0 + a1;

    // ---- all-lane epilogue: lane owns (row kq, col cc) ----
    float hval = tanhf(s[kq] + xv);
    packb[wv][(cc >> 3) * 32 + kq * 8 + (cc & 7)] = f2bf(hval);
    asm volatile("s_waitcnt lgkmcnt(0)" ::: "memory");
    __builtin_amdgcn_sched_barrier(0);

    // ---- ordered stores: h (sc1) -> out -> vmcnt(1) -> flag (sc1) ----
    unsigned short* hnext = hbuf + (size_t)((t + 1) & 1) * 65536 + g * 4096;
    if (ln < 8) {
      u32x4 pk = *(const u32x4*)(&packb[wv][ln * 8]);
      unsigned short* dp = hnext + ks_w * 128 + half * 64 + ln * 8;
      asm volatile("global_store_dwordx4 %0, %1, off sc1"
                   :: "v"(dp), "v"(pk) : "memory");
    }
    asm volatile("global_store_dword %0, %1, off"
                 :: "v"((float*)xp), "v"(hval) : "memory");
    asm volatile("s_waitcnt vmcnt(1)" ::: "memory");   // h-store done; out may fly
    if (ln == 0) {
      unsigned fv = (unsigned)(t + 1);
      const unsigned int* fq = flags + g * 64 + w * 8 + wv;
      asm volatile("global_store_dword %0, %1, off sc1"
                   :: "v"(fq), "v"(fv) : "memory");
    }
  }
}

extern "C" void kernel_launch(void* const* d_in, const int* in_sizes, int n_in,
                              void* d_out, int out_size, void* d_ws, size_t ws_size,
                              hipStream_t stream) {
  const float* x  = (const float*)d_in[0];
  const float* h0 = (const float*)d_in[1];
  const float* Wi = (const float*)d_in[2];
  const float* bi = (const float*)d_in[3];
  const float* Wh = (const float*)d_in[4];
  float* out = (float*)d_out;
  char* ws = (char*)d_ws;
  unsigned short* wsWi  = (unsigned short*)(ws + WSWI_OFF);
  unsigned short* wsWh2 = (unsigned short*)(ws + WSWH_OFF);
  unsigned short* hbuf  = (unsigned short*)(ws + HBUF_OFF);
  unsigned int* flags   = (unsigned int*)(ws + FLAG_OFF);

  prep_kernel<<<800, 256, 0, stream>>>(h0, Wi, Wh, wsWi, wsWh2, hbuf, flags);
  xi_gemm<<<dim3(8, 256), 256, 0, stream>>>(x, bi, wsWi, out);
  void* args[] = {(void*)&wsWh2, (void*)&out, (void*)&hbuf, (void*)&flags};
  (void)hipLaunchCooperativeKernel(reinterpret_cast<void*>(scan_kernel),
                                   dim3(NWGS), dim3(512), args, 0, stream);
}

// Round 10
// 2153.581 us; speedup vs baseline: 1.4986x; 1.4986x over previous
//
#include <hip/hip_runtime.h>

#define TT 512
#define BB 64
#define II 512
#define LL 1024
#define GROUPS 16
#define RPG 4            // batch rows per group
#define WPG 16           // WGs per group (64 cols each)
#define NWGS (GROUPS * WPG)

typedef __bf16 bf16x8 __attribute__((ext_vector_type(8)));
typedef float f32x4 __attribute__((ext_vector_type(4)));
typedef unsigned int u32x4 __attribute__((ext_vector_type(4)));

// ---------- workspace layout (bytes) ----------
// wsWi : Wi frag-ordered bf16 (xi_gemm)                          = 1 MiB
// wsWh2: Wh frag-ordered bf16 [16 w][4 n4][32 ks][64 l][8e]      = 2 MiB
// hbuf : ping-pong compact H  2 x [16 g][32 ks][4 kq][4 r][8e]   = 256 KiB
// flags: [16 g][64] uints — one per producer WAVE (w*4+wv)       = 4 KiB
#define WSWI_OFF 0u
#define WSWH_OFF (1u << 20)
#define HBUF_OFF (3u << 20)
#define FLAG_OFF ((3u << 20) + (1u << 18))

__device__ __forceinline__ unsigned short f2bf(float f) {
  unsigned int u = __builtin_bit_cast(unsigned int, f);
  u += 0x7fffu + ((u >> 16) & 1u);   // round-to-nearest-even (inputs finite)
  return (unsigned short)(u >> 16);
}

__device__ __forceinline__ bf16x8 ld_frag(const unsigned short* p) {
  return __builtin_bit_cast(bf16x8, *(const uint4*)p);
}

// ============================================================
// prep: frag-order Wi (xi_gemm), Wh2 (scan), compact h0; zero flags.
// ============================================================
__global__ __launch_bounds__(256) void prep_kernel(
    const float* __restrict__ h0, const float* __restrict__ Wi,
    const float* __restrict__ Wh, unsigned short* __restrict__ wsWi,
    unsigned short* __restrict__ wsWh2, unsigned short* __restrict__ hbuf,
    unsigned int* __restrict__ flags) {
  int idx = blockIdx.x * 256 + threadIdx.x;
  if (idx < GROUPS * 64) flags[idx] = 0u;
  const float* src;
  unsigned short* dst;
  if (idx < 65536) {                       // Wi slots (for xi_gemm)
    int ln = idx & 63, s = idx >> 6;
    int nsub = s & 7, s2 = s >> 3, ks = s2 & 15, bn = s2 >> 4;
    int n = bn * 128 + nsub * 16 + (ln & 15);
    int k = ks * 32 + (ln >> 4) * 8;
    src = Wi + (size_t)n * II + k;
    dst = wsWi + (size_t)idx * 8;
  } else if (idx < 196608) {               // Wh2 slots [w:16][n4:4][ks:32][l:64]
    int o = idx - 65536;
    int l = o & 63, s = o >> 6;
    int ks = s & 31, s2 = s >> 5;
    int n4 = s2 & 3, w = s2 >> 2;
    int col = w * 64 + n4 * 16 + (l & 15);
    int k = ks * 32 + (l >> 4) * 8;
    src = Wh + (size_t)col * LL + k;
    dst = wsWh2 + (size_t)o * 8;
  } else if (idx < 204800) {               // h0 compact slots [g][ks][kq][r][8e]
    int o = idx - 196608;
    int r = o & 3, kq = (o >> 2) & 3, ks = (o >> 4) & 31, g = o >> 9;
    src = h0 + (size_t)(g * RPG + r) * LL + ks * 32 + kq * 8;
    dst = hbuf + (size_t)o * 8;
  } else {
    return;
  }
  float4 a0 = *(const float4*)src;
  float4 a1 = *(const float4*)(src + 4);
  uint4 p;
  p.x = f2bf(a0.x) | ((unsigned)f2bf(a0.y) << 16);
  p.y = f2bf(a0.z) | ((unsigned)f2bf(a0.w) << 16);
  p.z = f2bf(a1.x) | ((unsigned)f2bf(a1.y) << 16);
  p.w = f2bf(a1.z) | ((unsigned)f2bf(a1.w) << 16);
  *(uint4*)dst = p;
}

// ============================================================
// xi = x @ Wi^T + bi  -> d_out (reused as xi buffer) [unchanged]
// ============================================================
__global__ __launch_bounds__(256) void xi_gemm(
    const float* __restrict__ x, const float* __restrict__ bi,
    const unsigned short* __restrict__ wsWi, float* __restrict__ out) {
  __shared__ unsigned short As[8 * 64 * 8];
  __shared__ unsigned short Bs[8 * 64 * 8];
  const int tid = threadIdx.x;
  const int ln = tid & 63;
  const int wv = tid >> 6;
  const int wm = wv >> 1, wn = wv & 1;
  const int bn = blockIdx.x;
  const int Mbase = blockIdx.y * 128;
  const int Nbase = bn * 128;

  f32x4 acc[4][4] = {};

  for (int ks = 0; ks < 16; ++ks) {
    __syncthreads();
#pragma unroll
    for (int i = 0; i < 2; ++i) {
      int slot = tid + 256 * i;
      int msub = slot >> 6;
      int l2 = slot & 63;
      const float* src =
          x + (size_t)(Mbase + msub * 16 + (l2 & 15)) * II + ks * 32 + (l2 >> 4) * 8;
      float4 a0 = *(const float4*)src;
      float4 a1 = *(const float4*)(src + 4);
      uint4 p;
      p.x = f2bf(a0.x) | ((unsigned)f2bf(a0.y) << 16);
      p.y = f2bf(a0.z) | ((unsigned)f2bf(a0.w) << 16);
      p.z = f2bf(a1.x) | ((unsigned)f2bf(a1.y) << 16);
      p.w = f2bf(a1.z) | ((unsigned)f2bf(a1.w) << 16);
      *(uint4*)(As + slot * 8) = p;
      const uint4* bsrc = (const uint4*)(wsWi + (size_t)(bn * 16 + ks) * 4096) + slot;
      *(uint4*)(Bs + slot * 8) = *bsrc;
    }
    __syncthreads();
    bf16x8 af[4];
#pragma unroll
    for (int m = 0; m < 4; ++m)
      af[m] = ld_frag(As + ((wm * 4 + m) * 64 + ln) * 8);
#pragma unroll
    for (int n = 0; n < 4; ++n) {
      bf16x8 bf = ld_frag(Bs + ((wn * 4 + n) * 64 + ln) * 8);
#pragma unroll
      for (int m = 0; m < 4; ++m)
        acc[m][n] = __builtin_amdgcn_mfma_f32_16x16x32_bf16(af[m], bf, acc[m][n], 0, 0, 0);
    }
  }
#pragma unroll
  for (int n = 0; n < 4; ++n) {
    int col = Nbase + wn * 64 + n * 16 + (ln & 15);
    float bv = bi[col];
#pragma unroll
    for (int m = 0; m < 4; ++m) {
      int row0 = Mbase + wm * 64 + m * 16 + (ln >> 4) * 4;
#pragma unroll
      for (int r = 0; r < 4; ++r)
        out[(size_t)(row0 + r) * LL + col] = acc[m][n][r] + bv;
    }
  }
}

// ============================================================
// Batch-grouped persistent scan v4 = r6 topology + r8 schedule.
// 16 groups x 4 rows; 16 WGs/group x 256 thr (4 waves x 16 cols).
// B in LDS (128 KB, staged once). Per step: partial-order poll
// (2 producer flags/thread) -> 8 KB gather (2 x dwordx4 sc1) ->
// hA double-buffer -> ONE barrier -> 32 MFMA -> all-lane tanh ->
// h-store (sc1) -> out-store -> vmcnt(1) -> per-wave flag.
// ============================================================
__global__ __launch_bounds__(256, 1) void scan_kernel(
    const unsigned short* __restrict__ wsWh2, float* __restrict__ out,
    unsigned short* __restrict__ hbuf, unsigned int* __restrict__ flags) {
  extern __shared__ char smem[];
  unsigned short* Bfrag = (unsigned short*)smem;              // 128 KiB
  unsigned short* hA    = (unsigned short*)(smem + 131072);   // 2 x 8 KiB
  unsigned short* packb = (unsigned short*)(smem + 147456);   // 4 x 128 B

  const int tid = threadIdx.x;
  const int ln = tid & 63;
  const int wv = tid >> 6;                 // 0..3 : 16-col subtile
  const int g = blockIdx.x >> 4;           // group
  const int w = blockIdx.x & 15;           // 64-col slice within group
  const int kq = ln >> 4;                  // batch row this lane owns
  const int rdup = ln & 3;
  const int cc = ln & 15;                  // col within wave's 16
  const int ks_w = w * 2 + (wv >> 1);      // wave's compact-h ks slot
  const int half = wv & 1;

  { // stage this WG's Wh slice (128 KiB) into LDS once
    const uint4* src = (const uint4*)(wsWh2 + (size_t)w * 65536);
    uint4* dst = (uint4*)Bfrag;
#pragma unroll
    for (int i = 0; i < 32; ++i) dst[tid + 256 * i] = src[tid + 256 * i];
  }
  __syncthreads();

  // ---- this thread's two gather chunks and their producer flags ----
  const int c0 = tid, c1 = tid + 256;
  const int ks0 = c0 >> 4, kq0 = (c0 >> 2) & 3;
  const int f0i = (ks0 >> 1) * 4 + (ks0 & 1) * 2 + (kq0 >> 1);
  const unsigned int* fpa = flags + g * 64 + f0i;
  const unsigned int* fpb = fpa + 32;      // chunk c1 -> ks+16 -> flag+32

  const unsigned short* Bb = Bfrag + wv * 16384;

  for (int t = 0; t < TT; ++t) {
    // ---- xi prefetch (plain cached; drained at gather vmcnt(0)) ----
    float xv;
    const float* xp = out + (size_t)t * 65536 + (size_t)(g * RPG + kq) * LL +
                      w * 64 + wv * 16 + cc;
    asm volatile("global_load_dword %0, %1, off" : "=&v"(xv) : "v"(xp) : "memory");

    // ---- partial-order wait: only this thread's 2 producers ----
    if (t > 0) {
      unsigned fa, fb;
      do {
        fa = __hip_atomic_load(fpa, __ATOMIC_RELAXED, __HIP_MEMORY_SCOPE_AGENT);
        fb = __hip_atomic_load(fpb, __ATOMIC_RELAXED, __HIP_MEMORY_SCOPE_AGENT);
      } while (__all((int)fa >= t && (int)fb >= t) == 0);
    }
    __builtin_amdgcn_sched_barrier(0);

    // ---- shared gather: 8 KB group state, 2 x 16B per thread, sc1 ----
    const unsigned short* hcur = hbuf + (size_t)(t & 1) * 65536 + g * 4096;
    u32x4 hv0, hv1;
    asm volatile("global_load_dwordx4 %0, %1, off sc1"
                 : "=&v"(hv0) : "v"(hcur + c0 * 8) : "memory");
    asm volatile("global_load_dwordx4 %0, %1, off sc1"
                 : "=&v"(hv1) : "v"(hcur + c1 * 8) : "memory");
    asm volatile("s_waitcnt vmcnt(0)" ::: "memory");
    __builtin_amdgcn_sched_barrier(0);
    unsigned short* hw = hA + (t & 1) * 4096;
    *(u32x4*)(hw + c0 * 8) = hv0;
    *(u32x4*)(hw + c1 * 8) = hv1;
    __syncthreads();                       // the ONE block barrier per step

    // ---- MFMA: K=1024, A from LDS (broadcast), B from LDS ----
    f32x4 a0 = {}, a1 = {};
#pragma unroll
    for (int ks = 0; ks < 32; ks += 2) {
      bf16x8 A0 = ld_frag(hw + (ks * 16 + kq * 4 + rdup) * 8);
      bf16x8 A1 = ld_frag(hw + ((ks + 1) * 16 + kq * 4 + rdup) * 8);
      bf16x8 B0 = ld_frag(Bb + (ks * 64 + ln) * 8);
      bf16x8 B1 = ld_frag(Bb + ((ks + 1) * 64 + ln) * 8);
      a0 = __builtin_amdgcn_mfma_f32_16x16x32_bf16(A0, B0, a0, 0, 0, 0);
      a1 = __builtin_amdgcn_mfma_f32_16x16x32_bf16(A1, B1, a1, 0, 0, 0);
    }
    f32x4 s = a0 + a1;

    // ---- all-lane epilogue: lane owns (row kq, col cc) ----
    float hval = tanhf(s[kq] + xv);
    packb[wv * 64 + (cc >> 3) * 32 + kq * 8 + (cc & 7)] = f2bf(hval);
    asm volatile("s_waitcnt lgkmcnt(0)" ::: "memory");
    __builtin_amdgcn_sched_barrier(0);

    // ---- ordered stores: h (sc1) -> out -> vmcnt(1) -> flag (sc1) ----
    unsigned short* hnext = hbuf + (size_t)((t + 1) & 1) * 65536 + g * 4096;
    if (ln < 8) {
      u32x4 pk = *(const u32x4*)(packb + wv * 64 + ln * 8);
      unsigned short* dp = hnext + ks_w * 128 + half * 64 + ln * 8;
      asm volatile("global_store_dwordx4 %0, %1, off sc1"
                   :: "v"(dp), "v"(pk) : "memory");
    }
    asm volatile("global_store_dword %0, %1, off"
                 :: "v"((float*)xp), "v"(hval) : "memory");
    asm volatile("s_waitcnt vmcnt(1)" ::: "memory");   // h-store done; out may fly
    if (ln == 0) {
      unsigned fv = (unsigned)(t + 1);
      const unsigned int* fq = flags + g * 64 + w * 4 + wv;
      asm volatile("global_store_dword %0, %1, off sc1"
                   :: "v"(fq), "v"(fv) : "memory");
    }
  }
}

extern "C" void kernel_launch(void* const* d_in, const int* in_sizes, int n_in,
                              void* d_out, int out_size, void* d_ws, size_t ws_size,
                              hipStream_t stream) {
  const float* x  = (const float*)d_in[0];
  const float* h0 = (const float*)d_in[1];
  const float* Wi = (const float*)d_in[2];
  const float* bi = (const float*)d_in[3];
  const float* Wh = (const float*)d_in[4];
  float* out = (float*)d_out;
  char* ws = (char*)d_ws;
  unsigned short* wsWi  = (unsigned short*)(ws + WSWI_OFF);
  unsigned short* wsWh2 = (unsigned short*)(ws + WSWH_OFF);
  unsigned short* hbuf  = (unsigned short*)(ws + HBUF_OFF);
  unsigned int* flags   = (unsigned int*)(ws + FLAG_OFF);

  prep_kernel<<<800, 256, 0, stream>>>(h0, Wi, Wh, wsWi, wsWh2, hbuf, flags);
  xi_gemm<<<dim3(8, 256), 256, 0, stream>>>(x, bi, wsWi, out);
  void* args[] = {(void*)&wsWh2, (void*)&out, (void*)&hbuf, (void*)&flags};
  (void)hipLaunchCooperativeKernel(reinterpret_cast<void*>(scan_kernel),
                                   dim3(NWGS), dim3(256), args, 147968, stream);
}

// Round 12
// 1776.069 us; speedup vs baseline: 1.8171x; 1.2126x over previous
//
#include <hip/hip_runtime.h>

#define TT 512
#define BB 64
#define II 512
#define LL 1024
#define GROUPS 16
#define RPG 4            // batch rows per group
#define WPG 16           // WGs per group (64 cols each)
#define NWGS (GROUPS * WPG)

typedef __bf16 bf16x8 __attribute__((ext_vector_type(8)));
typedef float f32x4 __attribute__((ext_vector_type(4)));
typedef unsigned int u32x4 __attribute__((ext_vector_type(4)));

// ---------- workspace layout (bytes) ----------
// wsWi : Wi frag-ordered bf16 (xi_gemm)                          = 1 MiB
// wsWh2: Wh frag-ordered bf16 [16 w][4 n4][32 ks][64 l][8e]      = 2 MiB
// hbuf : ping-pong compact H  2 x [16 g][32 ks][4 kq][4 r][8e]   = 256 KiB
// flags: [16 g][64] u16 — one per producer WAVE, 128B/group = 1 line
#define WSWI_OFF 0u
#define WSWH_OFF (1u << 20)
#define HBUF_OFF (3u << 20)
#define FLAG_OFF ((3u << 20) + (1u << 18))

__device__ __forceinline__ unsigned short f2bf(float f) {
  unsigned int u = __builtin_bit_cast(unsigned int, f);
  u += 0x7fffu + ((u >> 16) & 1u);   // round-to-nearest-even (inputs finite)
  return (unsigned short)(u >> 16);
}

__device__ __forceinline__ bf16x8 ld_frag(const unsigned short* p) {
  return __builtin_bit_cast(bf16x8, *(const uint4*)p);
}

// ============================================================
// prep: frag-order Wi (xi_gemm), Wh2 (scan), compact h0; zero flags.
// ============================================================
__global__ __launch_bounds__(256) void prep_kernel(
    const float* __restrict__ h0, const float* __restrict__ Wi,
    const float* __restrict__ Wh, unsigned short* __restrict__ wsWi,
    unsigned short* __restrict__ wsWh2, unsigned short* __restrict__ hbuf,
    unsigned int* __restrict__ flags32) {
  int idx = blockIdx.x * 256 + threadIdx.x;
  if (idx < 512) flags32[idx] = 0u;        // 2048 B of u16 flags
  const float* src;
  unsigned short* dst;
  if (idx < 65536) {                       // Wi slots (for xi_gemm)
    int ln = idx & 63, s = idx >> 6;
    int nsub = s & 7, s2 = s >> 3, ks = s2 & 15, bn = s2 >> 4;
    int n = bn * 128 + nsub * 16 + (ln & 15);
    int k = ks * 32 + (ln >> 4) * 8;
    src = Wi + (size_t)n * II + k;
    dst = wsWi + (size_t)idx * 8;
  } else if (idx < 196608) {               // Wh2 slots [w:16][n4:4][ks:32][l:64]
    int o = idx - 65536;
    int l = o & 63, s = o >> 6;
    int ks = s & 31, s2 = s >> 5;
    int n4 = s2 & 3, w = s2 >> 2;
    int col = w * 64 + n4 * 16 + (l & 15);
    int k = ks * 32 + (l >> 4) * 8;
    src = Wh + (size_t)col * LL + k;
    dst = wsWh2 + (size_t)o * 8;
  } else if (idx < 204800) {               // h0 compact slots [g][ks][kq][r][8e]
    int o = idx - 196608;
    int r = o & 3, kq = (o >> 2) & 3, ks = (o >> 4) & 31, g = o >> 9;
    src = h0 + (size_t)(g * RPG + r) * LL + ks * 32 + kq * 8;
    dst = hbuf + (size_t)o * 8;
  } else {
    return;
  }
  float4 a0 = *(const float4*)src;
  float4 a1 = *(const float4*)(src + 4);
  uint4 p;
  p.x = f2bf(a0.x) | ((unsigned)f2bf(a0.y) << 16);
  p.y = f2bf(a0.z) | ((unsigned)f2bf(a0.w) << 16);
  p.z = f2bf(a1.x) | ((unsigned)f2bf(a1.y) << 16);
  p.w = f2bf(a1.z) | ((unsigned)f2bf(a1.w) << 16);
  *(uint4*)dst = p;
}

// ============================================================
// xi = x @ Wi^T + bi  -> d_out (reused as xi buffer) [unchanged]
// ============================================================
__global__ __launch_bounds__(256) void xi_gemm(
    const float* __restrict__ x, const float* __restrict__ bi,
    const unsigned short* __restrict__ wsWi, float* __restrict__ out) {
  __shared__ unsigned short As[8 * 64 * 8];
  __shared__ unsigned short Bs[8 * 64 * 8];
  const int tid = threadIdx.x;
  const int ln = tid & 63;
  const int wv = tid >> 6;
  const int wm = wv >> 1, wn = wv & 1;
  const int bn = blockIdx.x;
  const int Mbase = blockIdx.y * 128;
  const int Nbase = bn * 128;

  f32x4 acc[4][4] = {};

  for (int ks = 0; ks < 16; ++ks) {
    __syncthreads();
#pragma unroll
    for (int i = 0; i < 2; ++i) {
      int slot = tid + 256 * i;
      int msub = slot >> 6;
      int l2 = slot & 63;
      const float* src =
          x + (size_t)(Mbase + msub * 16 + (l2 & 15)) * II + ks * 32 + (l2 >> 4) * 8;
      float4 a0 = *(const float4*)src;
      float4 a1 = *(const float4*)(src + 4);
      uint4 p;
      p.x = f2bf(a0.x) | ((unsigned)f2bf(a0.y) << 16);
      p.y = f2bf(a0.z) | ((unsigned)f2bf(a0.w) << 16);
      p.z = f2bf(a1.x) | ((unsigned)f2bf(a1.y) << 16);
      p.w = f2bf(a1.z) | ((unsigned)f2bf(a1.w) << 16);
      *(uint4*)(As + slot * 8) = p;
      const uint4* bsrc = (const uint4*)(wsWi + (size_t)(bn * 16 + ks) * 4096) + slot;
      *(uint4*)(Bs + slot * 8) = *bsrc;
    }
    __syncthreads();
    bf16x8 af[4];
#pragma unroll
    for (int m = 0; m < 4; ++m)
      af[m] = ld_frag(As + ((wm * 4 + m) * 64 + ln) * 8);
#pragma unroll
    for (int n = 0; n < 4; ++n) {
      bf16x8 bf = ld_frag(Bs + ((wn * 4 + n) * 64 + ln) * 8);
#pragma unroll
      for (int m = 0; m < 4; ++m)
        acc[m][n] = __builtin_amdgcn_mfma_f32_16x16x32_bf16(af[m], bf, acc[m][n], 0, 0, 0);
    }
  }
#pragma unroll
  for (int n = 0; n < 4; ++n) {
    int col = Nbase + wn * 64 + n * 16 + (ln & 15);
    float bv = bi[col];
#pragma unroll
    for (int m = 0; m < 4; ++m) {
      int row0 = Mbase + wm * 64 + m * 16 + (ln >> 4) * 4;
#pragma unroll
      for (int r = 0; r < 4; ++r)
        out[(size_t)(row0 + r) * LL + col] = acc[m][n][r] + bv;
    }
  }
}

// ============================================================
// Batch-grouped persistent scan v6 — consolidated.
// 16 groups x 4 rows; 16 WGs/group x 4 waves (64 cols/WG).
// Per-WAVE u16 flags, ALL 64 in ONE 128B line per group.
// Per step: partial-order poll (2 u16 flags) -> 8 KB gather
// (2 x dwordx4 sc1) -> hA dbuf -> ONE barrier -> 32 MFMA ->
// all-lane tanh -> h-store sc1 -> vmcnt(0) -> wave flag (u16)
// -> out store -> xi prefetch for t+1.
// ============================================================
__global__ __launch_bounds__(256, 1) void scan_kernel(
    const unsigned short* __restrict__ wsWh2, float* __restrict__ out,
    unsigned short* __restrict__ hbuf, unsigned short* __restrict__ flags) {
  extern __shared__ char smem[];
  unsigned short* Bfrag = (unsigned short*)smem;              // 128 KiB
  unsigned short* hA    = (unsigned short*)(smem + 131072);   // 2 x 8 KiB
  unsigned short* packb = (unsigned short*)(smem + 147456);   // 4 x 128 B

  const int tid = threadIdx.x;
  const int ln = tid & 63;
  const int wv = tid >> 6;                 // 0..3 : 16-col subtile
  const int g = blockIdx.x >> 4;           // group
  const int w = blockIdx.x & 15;           // 64-col slice within group
  const int kq = ln >> 4;                  // batch row this lane owns
  const int rdup = ln & 3;
  const int cc = ln & 15;                  // col within wave's 16
  const int ks_w = w * 2 + (wv >> 1);      // wave's compact-h ks slot
  const int half = wv & 1;

  { // stage this WG's Wh slice (128 KiB) into LDS once
    const uint4* src = (const uint4*)(wsWh2 + (size_t)w * 65536);
    uint4* dst = (uint4*)Bfrag;
#pragma unroll
    for (int i = 0; i < 32; ++i) dst[tid + 256 * i] = src[tid + 256 * i];
  }
  __syncthreads();

  // ---- this thread's two gather chunks and their producer-wave flags ----
  const int c0 = tid, c1 = tid + 256;
  const int ks0 = c0 >> 4;
  const int f0i = (ks0 >> 1) * 4 + (ks0 & 1) * 2 + ((c0 >> 3) & 1);
  const unsigned short* fpa = flags + g * 64 + f0i;   // one 128B line/group
  const unsigned short* fpb = fpa + 32;               // chunk c1 -> +32

  const unsigned short* Bb = Bfrag + wv * 16384;

  // my output cell (row kq of group, col w*64+wv*16+cc); also my xi address
  const size_t ocell = (size_t)(g * RPG + kq) * LL + w * 64 + wv * 16 + cc;

  // ---- prologue: prefetch xi(0) ----
  float xv_next;
  {
    const float* xp0 = out + ocell;        // t = 0
    asm volatile("global_load_dword %0, %1, off"
                 : "=&v"(xv_next) : "v"(xp0) : "memory");
  }

  for (int t = 0; t < TT; ++t) {
    // ---- partial-order wait: 2 producer-wave u16 flags (same line) ----
    if (t > 0) {
      unsigned fa, fb;
      do {
        asm volatile(
            "global_load_ushort %0, %2, off sc1\n\t"
            "global_load_ushort %1, %3, off sc1\n\t"
            "s_waitcnt vmcnt(0)"
            : "=&v"(fa), "=&v"(fb) : "v"(fpa), "v"(fpb) : "memory");
      } while (__all((int)fa >= t && (int)fb >= t) == 0);
    }
    __builtin_amdgcn_sched_barrier(0);

    // ---- shared gather: 8 KB group state, 2 x 16B per thread, sc1 ----
    const unsigned short* hcur = hbuf + (size_t)(t & 1) * 65536 + g * 4096;
    u32x4 hv0, hv1;
    asm volatile("global_load_dwordx4 %0, %1, off sc1"
                 : "=&v"(hv0) : "v"(hcur + c0 * 8) : "memory");
    asm volatile("global_load_dwordx4 %0, %1, off sc1"
                 : "=&v"(hv1) : "v"(hcur + c1 * 8) : "memory");
    asm volatile("s_waitcnt vmcnt(0)" ::: "memory");
    __builtin_amdgcn_sched_barrier(0);
    unsigned short* hw = hA + (t & 1) * 4096;
    *(u32x4*)(hw + c0 * 8) = hv0;
    *(u32x4*)(hw + c1 * 8) = hv1;
    float xv = xv_next;                    // prefetch landed (covered by vmcnt(0))
    __syncthreads();                       // the ONE block barrier per step

    // ---- MFMA: K=1024, A from LDS (broadcast), B from LDS ----
    f32x4 a0 = {}, a1 = {};
#pragma unroll
    for (int ks = 0; ks < 32; ks += 2) {
      bf16x8 A0 = ld_frag(hw + (ks * 16 + kq * 4 + rdup) * 8);
      bf16x8 A1 = ld_frag(hw + ((ks + 1) * 16 + kq * 4 + rdup) * 8);
      bf16x8 B0 = ld_frag(Bb + (ks * 64 + ln) * 8);
      bf16x8 B1 = ld_frag(Bb + ((ks + 1) * 64 + ln) * 8);
      a0 = __builtin_amdgcn_mfma_f32_16x16x32_bf16(A0, B0, a0, 0, 0, 0);
      a1 = __builtin_amdgcn_mfma_f32_16x16x32_bf16(A1, B1, a1, 0, 0, 0);
    }
    f32x4 s = a0 + a1;

    // ---- all-lane epilogue: lane owns (row kq, col cc) ----
    float hval = tanhf(s[kq] + xv);
    packb[wv * 64 + (cc >> 3) * 32 + kq * 8 + (cc & 7)] = f2bf(hval);
    asm volatile("s_waitcnt lgkmcnt(0)" ::: "memory");
    __builtin_amdgcn_sched_barrier(0);

    // ---- publish: h (sc1) -> vmcnt(0) -> wave flag (u16 sc1) ----
    unsigned short* hnext = hbuf + (size_t)((t + 1) & 1) * 65536 + g * 4096;
    if (ln < 8) {
      u32x4 pk = *(const u32x4*)(packb + wv * 64 + ln * 8);
      unsigned short* dp = hnext + ks_w * 128 + half * 64 + ln * 8;
      asm volatile("global_store_dwordx4 %0, %1, off sc1"
                   :: "v"(dp), "v"(pk) : "memory");
    }
    asm volatile("s_waitcnt vmcnt(0)" ::: "memory");   // h-ack only (queue clean)
    if (ln == 0) {
      unsigned fv = (unsigned)(t + 1);
      const unsigned short* fq = flags + g * 64 + w * 4 + wv;
      asm volatile("global_store_short %0, %1, off sc1"
                   :: "v"(fq), "v"(fv) : "memory");
    }
    // ---- off-path: out store + xi prefetch for t+1 ----
    out[(size_t)t * 65536 + ocell] = hval;
    {
      int tn = (t + 1 < TT) ? (t + 1) : t;
      const float* xpn = out + (size_t)tn * 65536 + ocell;
      asm volatile("global_load_dword %0, %1, off"
                   : "=&v"(xv_next) : "v"(xpn) : "memory");
    }
  }
}

extern "C" void kernel_launch(void* const* d_in, const int* in_sizes, int n_in,
                              void* d_out, int out_size, void* d_ws, size_t ws_size,
                              hipStream_t stream) {
  const float* x  = (const float*)d_in[0];
  const float* h0 = (const float*)d_in[1];
  const float* Wi = (const float*)d_in[2];
  const float* bi = (const float*)d_in[3];
  const float* Wh = (const float*)d_in[4];
  float* out = (float*)d_out;
  char* ws = (char*)d_ws;
  unsigned short* wsWi  = (unsigned short*)(ws + WSWI_OFF);
  unsigned short* wsWh2 = (unsigned short*)(ws + WSWH_OFF);
  unsigned short* hbuf  = (unsigned short*)(ws + HBUF_OFF);
  unsigned int* flags32 = (unsigned int*)(ws + FLAG_OFF);
  unsigned short* flags = (unsigned short*)(ws + FLAG_OFF);

  prep_kernel<<<800, 256, 0, stream>>>(h0, Wi, Wh, wsWi, wsWh2, hbuf, flags32);
  xi_gemm<<<dim3(8, 256), 256, 0, stream>>>(x, bi, wsWi, out);
  void* args[] = {(void*)&wsWh2, (void*)&out, (void*)&hbuf, (void*)&flags};
  (void)hipLaunchCooperativeKernel(reinterpret_cast<void*>(scan_kernel),
                                   dim3(NWGS), dim3(256), args, 147968, stream);
}

// Round 14
// 1240.810 us; speedup vs baseline: 2.6010x; 1.4314x over previous
//
#include <hip/hip_runtime.h>

#define TT 512
#define BB 64
#define II 512
#define LL 1024
#define GROUPS 16
#define RPG 4            // batch rows per group
#define WPG 16           // WGs per group (64 cols each)
#define NWGS (GROUPS * WPG)

typedef __bf16 bf16x8 __attribute__((ext_vector_type(8)));
typedef float f32x4 __attribute__((ext_vector_type(4)));
typedef unsigned int u32x4 __attribute__((ext_vector_type(4)));

// ---------- workspace layout (bytes) ----------
// wsWi : Wi frag-ordered bf16 (xi_gemm)                          = 1 MiB
// wsWh2: Wh frag-ordered bf16 [16 w][4 n4][32 ks][64 l][8e]      = 2 MiB
// hbuf : ping-pong compact H  2 x [16 g][32 ks][4 kq][4 r][8e]   = 256 KiB
//        readiness tag = LSB of elements 0,2,4,6 of each 16B chunk
//        (LSB of the low half of each dword -> 4B-tear-proof)
#define WSWI_OFF 0u
#define WSWH_OFF (1u << 20)
#define HBUF_OFF (3u << 20)

__device__ __forceinline__ unsigned short f2bf(float f) {
  unsigned int u = __builtin_bit_cast(unsigned int, f);
  u += 0x7fffu + ((u >> 16) & 1u);   // round-to-nearest-even (inputs finite)
  return (unsigned short)(u >> 16);
}

__device__ __forceinline__ bf16x8 ld_frag(const unsigned short* p) {
  return __builtin_bit_cast(bf16x8, *(const uint4*)p);
}

// ============================================================
// prep: frag-order Wi (xi_gemm), Wh2 (scan), compact h0 (tag=0),
//       seed hbuf ping buffer 1 with tag=1 (kills t=1 false-positive:
//       zeros OR 0xAA poison both have LSB=0 == t=1's expected tag).
// ============================================================
__global__ __launch_bounds__(256) void prep_kernel(
    const float* __restrict__ h0, const float* __restrict__ Wi,
    const float* __restrict__ Wh, unsigned short* __restrict__ wsWi,
    unsigned short* __restrict__ wsWh2, unsigned short* __restrict__ hbuf) {
  int idx = blockIdx.x * 256 + threadIdx.x;
  const float* src;
  unsigned short* dst;
  bool tagme = false;
  if (idx < 65536) {                       // Wi slots (for xi_gemm)
    int ln = idx & 63, s = idx >> 6;
    int nsub = s & 7, s2 = s >> 3, ks = s2 & 15, bn = s2 >> 4;
    int n = bn * 128 + nsub * 16 + (ln & 15);
    int k = ks * 32 + (ln >> 4) * 8;
    src = Wi + (size_t)n * II + k;
    dst = wsWi + (size_t)idx * 8;
  } else if (idx < 196608) {               // Wh2 slots [w:16][n4:4][ks:32][l:64]
    int o = idx - 65536;
    int l = o & 63, s = o >> 6;
    int ks = s & 31, s2 = s >> 5;
    int n4 = s2 & 3, w = s2 >> 2;
    int col = w * 64 + n4 * 16 + (l & 15);
    int k = ks * 32 + (l >> 4) * 8;
    src = Wh + (size_t)col * LL + k;
    dst = wsWh2 + (size_t)o * 8;
  } else if (idx < 204800) {               // h0 compact slots [g][ks][kq][r][8e]
    int o = idx - 196608;
    int r = o & 3, kq = (o >> 2) & 3, ks = (o >> 4) & 31, g = o >> 9;
    src = h0 + (size_t)(g * RPG + r) * LL + ks * 32 + kq * 8;
    dst = hbuf + (size_t)o * 8;
    tagme = true;
  } else if (idx < 212992) {               // seed ping buffer 1: tag = 1
    int o = idx - 204800;
    uint4 p = {0x00010001u, 0x00010001u, 0x00010001u, 0x00010001u};
    *(uint4*)(hbuf + 65536 + (size_t)o * 8) = p;
    return;
  } else {
    return;
  }
  float4 a0 = *(const float4*)src;
  float4 a1 = *(const float4*)(src + 4);
  uint4 p;
  p.x = f2bf(a0.x) | ((unsigned)f2bf(a0.y) << 16);
  p.y = f2bf(a0.z) | ((unsigned)f2bf(a0.w) << 16);
  p.z = f2bf(a1.x) | ((unsigned)f2bf(a1.y) << 16);
  p.w = f2bf(a1.z) | ((unsigned)f2bf(a1.w) << 16);
  if (tagme) {                             // h0 tag = 0 on all even elements
    p.x &= ~1u; p.y &= ~1u; p.z &= ~1u; p.w &= ~1u;
  }
  *(uint4*)dst = p;
}

// ============================================================
// xi = x @ Wi^T + bi  -> d_out (reused as xi buffer) [unchanged]
// ============================================================
__global__ __launch_bounds__(256) void xi_gemm(
    const float* __restrict__ x, const float* __restrict__ bi,
    const unsigned short* __restrict__ wsWi, float* __restrict__ out) {
  __shared__ unsigned short As[8 * 64 * 8];
  __shared__ unsigned short Bs[8 * 64 * 8];
  const int tid = threadIdx.x;
  const int ln = tid & 63;
  const int wv = tid >> 6;
  const int wm = wv >> 1, wn = wv & 1;
  const int bn = blockIdx.x;
  const int Mbase = blockIdx.y * 128;
  const int Nbase = bn * 128;

  f32x4 acc[4][4] = {};

  for (int ks = 0; ks < 16; ++ks) {
    __syncthreads();
#pragma unroll
    for (int i = 0; i < 2; ++i) {
      int slot = tid + 256 * i;
      int msub = slot >> 6;
      int l2 = slot & 63;
      const float* src =
          x + (size_t)(Mbase + msub * 16 + (l2 & 15)) * II + ks * 32 + (l2 >> 4) * 8;
      float4 a0 = *(const float4*)src;
      float4 a1 = *(const float4*)(src + 4);
      uint4 p;
      p.x = f2bf(a0.x) | ((unsigned)f2bf(a0.y) << 16);
      p.y = f2bf(a0.z) | ((unsigned)f2bf(a0.w) << 16);
      p.z = f2bf(a1.x) | ((unsigned)f2bf(a1.y) << 16);
      p.w = f2bf(a1.z) | ((unsigned)f2bf(a1.w) << 16);
      *(uint4*)(As + slot * 8) = p;
      const uint4* bsrc = (const uint4*)(wsWi + (size_t)(bn * 16 + ks) * 4096) + slot;
      *(uint4*)(Bs + slot * 8) = *bsrc;
    }
    __syncthreads();
    bf16x8 af[4];
#pragma unroll
    for (int m = 0; m < 4; ++m)
      af[m] = ld_frag(As + ((wm * 4 + m) * 64 + ln) * 8);
#pragma unroll
    for (int n = 0; n < 4; ++n) {
      bf16x8 bf = ld_frag(Bs + ((wn * 4 + n) * 64 + ln) * 8);
#pragma unroll
      for (int m = 0; m < 4; ++m)
        acc[m][n] = __builtin_amdgcn_mfma_f32_16x16x32_bf16(af[m], bf, acc[m][n], 0, 0, 0);
    }
  }
#pragma unroll
  for (int n = 0; n < 4; ++n) {
    int col = Nbase + wn * 64 + n * 16 + (ln & 15);
    float bv = bi[col];
#pragma unroll
    for (int m = 0; m < 4; ++m) {
      int row0 = Mbase + wm * 64 + m * 16 + (ln >> 4) * 4;
#pragma unroll
      for (int r = 0; r < 4; ++r)
        out[(size_t)(row0 + r) * LL + col] = acc[m][n][r] + bv;
    }
  }
}

// ============================================================
// Batch-grouped persistent scan v7b — flagless, data-tagged.
// The poll IS the gather: consumer re-loads its 2 chunks (sc1)
// until the embedded LSB tags (all 4 dwords of each chunk) match
// parity (t>>1)&1. Producer stores h (sc1) and moves on — no
// drain, no flag. Buffer-1 seeded with tag=1 so t=1 cannot
// false-positive on initial contents.
// ============================================================
__global__ __launch_bounds__(256, 1) void scan_kernel(
    const unsigned short* __restrict__ wsWh2, float* __restrict__ out,
    unsigned short* __restrict__ hbuf) {
  extern __shared__ char smem[];
  unsigned short* Bfrag = (unsigned short*)smem;              // 128 KiB
  unsigned short* hA    = (unsigned short*)(smem + 131072);   // 2 x 8 KiB
  unsigned short* packb = (unsigned short*)(smem + 147456);   // 4 x 128 B

  const int tid = threadIdx.x;
  const int ln = tid & 63;
  const int wv = tid >> 6;                 // 0..3 : 16-col subtile
  const int g = blockIdx.x >> 4;           // group
  const int w = blockIdx.x & 15;           // 64-col slice within group
  const int kq = ln >> 4;                  // batch row this lane owns
  const int rdup = ln & 3;
  const int cc = ln & 15;                  // col within wave's 16
  const int ks_w = w * 2 + (wv >> 1);      // wave's compact-h ks slot
  const int half = wv & 1;

  { // stage this WG's Wh slice (128 KiB) into LDS once
    const uint4* src = (const uint4*)(wsWh2 + (size_t)w * 65536);
    uint4* dst = (uint4*)Bfrag;
#pragma unroll
    for (int i = 0; i < 32; ++i) dst[tid + 256 * i] = src[tid + 256 * i];
  }
  __syncthreads();

  const int c0 = tid, c1 = tid + 256;      // this thread's two 16B chunks
  const unsigned short* Bb = Bfrag + wv * 16384;

  // my output cell (row kq of group, col w*64+wv*16+cc); also my xi address
  const size_t ocell = (size_t)(g * RPG + kq) * LL + w * 64 + wv * 16 + cc;

  // ---- prologue: prefetch xi(0) ----
  float xv_next;
  asm volatile("global_load_dword %0, %1, off"
               : "=&v"(xv_next) : "v"(out + ocell) : "memory");

  for (int t = 0; t < TT; ++t) {
    const unsigned ptag = (unsigned)((t >> 1) & 1);        // expected tag
    const unsigned ntag = (unsigned)(((t + 1) >> 1) & 1);  // tag for h_{t+1}

    // ---- poll-gather: re-load own 2 chunks until all 8 tags match ----
    const unsigned short* hcur = hbuf + (size_t)(t & 1) * 65536 + g * 4096;
    const unsigned short* p0 = hcur + c0 * 8;
    const unsigned short* p1 = hcur + c1 * 8;
    u32x4 hv0, hv1;
    {
      int good;
      do {
        asm volatile(
            "global_load_dwordx4 %0, %2, off sc1\n\t"
            "global_load_dwordx4 %1, %3, off sc1\n\t"
            "s_waitcnt vmcnt(0)"
            : "=&v"(hv0), "=&v"(hv1) : "v"(p0), "v"(p1) : "memory");
        good = ((hv0[0] & 1) == ptag) & ((hv0[1] & 1) == ptag) &
               ((hv0[2] & 1) == ptag) & ((hv0[3] & 1) == ptag) &
               ((hv1[0] & 1) == ptag) & ((hv1[1] & 1) == ptag) &
               ((hv1[2] & 1) == ptag) & ((hv1[3] & 1) == ptag);
      } while (__all(good) == 0);
    }
    __builtin_amdgcn_sched_barrier(0);
    unsigned short* hw = hA + (t & 1) * 4096;
    *(u32x4*)(hw + c0 * 8) = hv0;
    *(u32x4*)(hw + c1 * 8) = hv1;
    float xv = xv_next;                    // xi landed under the poll
    __syncthreads();                       // the ONE block barrier per step

    // ---- MFMA: K=1024, A from LDS (broadcast), B from LDS; 4 chains ----
    f32x4 a0 = {}, a1 = {}, a2 = {}, a3 = {};
#pragma unroll
    for (int ks = 0; ks < 32; ks += 4) {
      bf16x8 A0 = ld_frag(hw + (ks * 16 + kq * 4 + rdup) * 8);
      bf16x8 A1 = ld_frag(hw + ((ks + 1) * 16 + kq * 4 + rdup) * 8);
      bf16x8 A2 = ld_frag(hw + ((ks + 2) * 16 + kq * 4 + rdup) * 8);
      bf16x8 A3 = ld_frag(hw + ((ks + 3) * 16 + kq * 4 + rdup) * 8);
      bf16x8 B0 = ld_frag(Bb + (ks * 64 + ln) * 8);
      bf16x8 B1 = ld_frag(Bb + ((ks + 1) * 64 + ln) * 8);
      bf16x8 B2 = ld_frag(Bb + ((ks + 2) * 64 + ln) * 8);
      bf16x8 B3 = ld_frag(Bb + ((ks + 3) * 64 + ln) * 8);
      a0 = __builtin_amdgcn_mfma_f32_16x16x32_bf16(A0, B0, a0, 0, 0, 0);
      a1 = __builtin_amdgcn_mfma_f32_16x16x32_bf16(A1, B1, a1, 0, 0, 0);
      a2 = __builtin_amdgcn_mfma_f32_16x16x32_bf16(A2, B2, a2, 0, 0, 0);
      a3 = __builtin_amdgcn_mfma_f32_16x16x32_bf16(A3, B3, a3, 0, 0, 0);
    }
    f32x4 s = (a0 + a1) + (a2 + a3);

    // ---- all-lane epilogue: lane owns (row kq, col cc) ----
    float hval = tanhf(s[kq] + xv);
    unsigned short hbf = f2bf(hval);
    if ((cc & 1) == 0)                     // even elements carry the tag
      hbf = (unsigned short)((hbf & ~1u) | ntag);
    packb[wv * 64 + (cc >> 3) * 32 + kq * 8 + (cc & 7)] = hbf;
    asm volatile("s_waitcnt lgkmcnt(0)" ::: "memory");
    __builtin_amdgcn_sched_barrier(0);

    // ---- publish h (sc1) — no drain, no flag; then out + xi(t+1) ----
    unsigned short* hnext = hbuf + (size_t)((t + 1) & 1) * 65536 + g * 4096;
    if (ln < 8) {
      u32x4 pk = *(const u32x4*)(packb + wv * 64 + ln * 8);
      unsigned short* dp = hnext + ks_w * 128 + half * 64 + ln * 8;
      asm volatile("global_store_dwordx4 %0, %1, off sc1"
                   :: "v"(dp), "v"(pk) : "memory");
    }
    out[(size_t)t * 65536 + ocell] = hval;
    {
      int tn = (t + 1 < TT) ? (t + 1) : t;
      asm volatile("global_load_dword %0, %1, off"
                   : "=&v"(xv_next) : "v"(out + (size_t)tn * 65536 + ocell)
                   : "memory");
    }
  }
}

extern "C" void kernel_launch(void* const* d_in, const int* in_sizes, int n_in,
                              void* d_out, int out_size, void* d_ws, size_t ws_size,
                              hipStream_t stream) {
  const float* x  = (const float*)d_in[0];
  const float* h0 = (const float*)d_in[1];
  const float* Wi = (const float*)d_in[2];
  const float* bi = (const float*)d_in[3];
  const float* Wh = (const float*)d_in[4];
  float* out = (float*)d_out;
  char* ws = (char*)d_ws;
  unsigned short* wsWi  = (unsigned short*)(ws + WSWI_OFF);
  unsigned short* wsWh2 = (unsigned short*)(ws + WSWH_OFF);
  unsigned short* hbuf  = (unsigned short*)(ws + HBUF_OFF);

  prep_kernel<<<832, 256, 0, stream>>>(h0, Wi, Wh, wsWi, wsWh2, hbuf);
  xi_gemm<<<dim3(8, 256), 256, 0, stream>>>(x, bi, wsWi, out);
  void* args[] = {(void*)&wsWh2, (void*)&out, (void*)&hbuf};
  (void)hipLaunchCooperativeKernel(reinterpret_cast<void*>(scan_kernel),
                                   dim3(NWGS), dim3(256), args, 147968, stream);
}

// Round 15
// 1058.970 us; speedup vs baseline: 3.0476x; 1.1717x over previous
//
#include <hip/hip_runtime.h>

#define TT 512
#define BB 64
#define II 512
#define LL 1024
#define GROUPS 16
#define RPG 4            // batch rows per group
#define WPG 16           // WGs per group (64 cols each)
#define NWGS (GROUPS * WPG)

typedef __bf16 bf16x8 __attribute__((ext_vector_type(8)));
typedef float f32x4 __attribute__((ext_vector_type(4)));
typedef unsigned int u32x4 __attribute__((ext_vector_type(4)));

// ---------- workspace layout (bytes) ----------
// wsWi : Wi frag-ordered bf16 (xi_gemm)                          = 1 MiB
// wsWh2: Wh frag-ordered bf16 [16 w][4 wv][32 ks][64 l][8e]      = 2 MiB
// hbuf : ping-pong compact H  2 x [16 g][32 ks][4 kq][4 r][8e]   = 256 KiB
//        readiness tag = LSB of even elements of each 16B chunk
#define WSWI_OFF 0u
#define WSWH_OFF (1u << 20)
#define HBUF_OFF (3u << 20)

__device__ __forceinline__ unsigned short f2bf(float f) {
  unsigned int u = __builtin_bit_cast(unsigned int, f);
  u += 0x7fffu + ((u >> 16) & 1u);   // round-to-nearest-even (inputs finite)
  return (unsigned short)(u >> 16);
}

__device__ __forceinline__ bf16x8 ld_frag(const unsigned short* p) {
  return __builtin_bit_cast(bf16x8, *(const uint4*)p);
}

// ============================================================
// prep: frag-order Wi (xi_gemm), Wh2 (scan), compact h0 (tag=0),
//       seed hbuf ping buffer 1 with tag=1 (t=1 false-positive guard).
// ============================================================
__global__ __launch_bounds__(256) void prep_kernel(
    const float* __restrict__ h0, const float* __restrict__ Wi,
    const float* __restrict__ Wh, unsigned short* __restrict__ wsWi,
    unsigned short* __restrict__ wsWh2, unsigned short* __restrict__ hbuf) {
  int idx = blockIdx.x * 256 + threadIdx.x;
  const float* src;
  unsigned short* dst;
  bool tagme = false;
  if (idx < 65536) {                       // Wi slots (for xi_gemm)
    int ln = idx & 63, s = idx >> 6;
    int nsub = s & 7, s2 = s >> 3, ks = s2 & 15, bn = s2 >> 4;
    int n = bn * 128 + nsub * 16 + (ln & 15);
    int k = ks * 32 + (ln >> 4) * 8;
    src = Wi + (size_t)n * II + k;
    dst = wsWi + (size_t)idx * 8;
  } else if (idx < 196608) {               // Wh2 slots [w:16][wv:4][ks:32][l:64]
    int o = idx - 65536;
    int l = o & 63, s = o >> 6;
    int ks = s & 31, s2 = s >> 5;
    int n4 = s2 & 3, w = s2 >> 2;
    int col = w * 64 + n4 * 16 + (l & 15);
    int k = ks * 32 + (l >> 4) * 8;
    src = Wh + (size_t)col * LL + k;
    dst = wsWh2 + (size_t)o * 8;
  } else if (idx < 204800) {               // h0 compact slots [g][ks][kq][r][8e]
    int o = idx - 196608;
    int r = o & 3, kq = (o >> 2) & 3, ks = (o >> 4) & 31, g = o >> 9;
    src = h0 + (size_t)(g * RPG + r) * LL + ks * 32 + kq * 8;
    dst = hbuf + (size_t)o * 8;
    tagme = true;
  } else if (idx < 212992) {               // seed ping buffer 1: tag = 1
    int o = idx - 204800;
    uint4 p = {0x00010001u, 0x00010001u, 0x00010001u, 0x00010001u};
    *(uint4*)(hbuf + 65536 + (size_t)o * 8) = p;
    return;
  } else {
    return;
  }
  float4 a0 = *(const float4*)src;
  float4 a1 = *(const float4*)(src + 4);
  uint4 p;
  p.x = f2bf(a0.x) | ((unsigned)f2bf(a0.y) << 16);
  p.y = f2bf(a0.z) | ((unsigned)f2bf(a0.w) << 16);
  p.z = f2bf(a1.x) | ((unsigned)f2bf(a1.y) << 16);
  p.w = f2bf(a1.z) | ((unsigned)f2bf(a1.w) << 16);
  if (tagme) {                             // h0 tag = 0 on all even elements
    p.x &= ~1u; p.y &= ~1u; p.z &= ~1u; p.w &= ~1u;
  }
  *(uint4*)dst = p;
}

// ============================================================
// xi = x @ Wi^T + bi  -> d_out (reused as xi buffer) [unchanged]
// ============================================================
__global__ __launch_bounds__(256) void xi_gemm(
    const float* __restrict__ x, const float* __restrict__ bi,
    const unsigned short* __restrict__ wsWi, float* __restrict__ out) {
  __shared__ unsigned short As[8 * 64 * 8];
  __shared__ unsigned short Bs[8 * 64 * 8];
  const int tid = threadIdx.x;
  const int ln = tid & 63;
  const int wv = tid >> 6;
  const int wm = wv >> 1, wn = wv & 1;
  const int bn = blockIdx.x;
  const int Mbase = blockIdx.y * 128;
  const int Nbase = bn * 128;

  f32x4 acc[4][4] = {};

  for (int ks = 0; ks < 16; ++ks) {
    __syncthreads();
#pragma unroll
    for (int i = 0; i < 2; ++i) {
      int slot = tid + 256 * i;
      int msub = slot >> 6;
      int l2 = slot & 63;
      const float* src =
          x + (size_t)(Mbase + msub * 16 + (l2 & 15)) * II + ks * 32 + (l2 >> 4) * 8;
      float4 a0 = *(const float4*)src;
      float4 a1 = *(const float4*)(src + 4);
      uint4 p;
      p.x = f2bf(a0.x) | ((unsigned)f2bf(a0.y) << 16);
      p.y = f2bf(a0.z) | ((unsigned)f2bf(a0.w) << 16);
      p.z = f2bf(a1.x) | ((unsigned)f2bf(a1.y) << 16);
      p.w = f2bf(a1.z) | ((unsigned)f2bf(a1.w) << 16);
      *(uint4*)(As + slot * 8) = p;
      const uint4* bsrc = (const uint4*)(wsWi + (size_t)(bn * 16 + ks) * 4096) + slot;
      *(uint4*)(Bs + slot * 8) = *bsrc;
    }
    __syncthreads();
    bf16x8 af[4];
#pragma unroll
    for (int m = 0; m < 4; ++m)
      af[m] = ld_frag(As + ((wm * 4 + m) * 64 + ln) * 8);
#pragma unroll
    for (int n = 0; n < 4; ++n) {
      bf16x8 bf = ld_frag(Bs + ((wn * 4 + n) * 64 + ln) * 8);
#pragma unroll
      for (int m = 0; m < 4; ++m)
        acc[m][n] = __builtin_amdgcn_mfma_f32_16x16x32_bf16(af[m], bf, acc[m][n], 0, 0, 0);
    }
  }
#pragma unroll
  for (int n = 0; n < 4; ++n) {
    int col = Nbase + wn * 64 + n * 16 + (ln & 15);
    float bv = bi[col];
#pragma unroll
    for (int m = 0; m < 4; ++m) {
      int row0 = Mbase + wm * 64 + m * 16 + (ln >> 4) * 4;
#pragma unroll
      for (int r = 0; r < 4; ++r)
        out[(size_t)(row0 + r) * LL + col] = acc[m][n][r] + bv;
    }
  }
}

// ============================================================
// Batch-grouped persistent scan v8 — flagless data-tagged (r14)
// + B pinned in 128 VGPRs via asm loads (remat-proof, r9-style).
// Per-step LDS traffic drops from 64 ds_read_b128/wave to 32
// broadcast A-reads; LDS 144 KB -> 17 KB.
// ============================================================
__global__ __launch_bounds__(256, 1) void scan_kernel(
    const unsigned short* __restrict__ wsWh2, float* __restrict__ out,
    unsigned short* __restrict__ hbuf) {
  __shared__ unsigned short hA[2][4096];      // 2 x 8 KiB compact H
  __shared__ unsigned short packb[4][64];     // per-wave pack, 128 B each

  const int tid = threadIdx.x;
  const int ln = tid & 63;
  const int wv = tid >> 6;                 // 0..3 : 16-col subtile
  const int g = blockIdx.x >> 4;           // group
  const int w = blockIdx.x & 15;           // 64-col slice within group
  const int kq = ln >> 4;                  // batch row this lane owns
  const int rdup = ln & 3;
  const int cc = ln & 15;                  // col within wave's 16
  const int ks_w = w * 2 + (wv >> 1);      // wave's compact-h ks slot
  const int half = wv & 1;

  // ---- B-frags pinned in VGPRs via asm loads (32 x 16B = 128 VGPR) ----
  u32x4 Breg[32];
  {
    const unsigned short* bsrc = wsWh2 + (size_t)(w * 4 + wv) * 16384 + ln * 8;
#pragma unroll
    for (int i = 0; i < 8; ++i) {
      const unsigned short* bp = bsrc + i * 2048;   // 4 ks per iter (4 KB)
      asm volatile(
          "global_load_dwordx4 %0, %4, off\n\t"
          "global_load_dwordx4 %1, %4, off offset:1024\n\t"
          "global_load_dwordx4 %2, %4, off offset:2048\n\t"
          "global_load_dwordx4 %3, %4, off offset:3072"
          : "=&v"(Breg[i * 4]), "=&v"(Breg[i * 4 + 1]),
            "=&v"(Breg[i * 4 + 2]), "=&v"(Breg[i * 4 + 3])
          : "v"(bp) : "memory");
    }
    asm volatile("s_waitcnt vmcnt(0)" ::: "memory");
    __builtin_amdgcn_sched_barrier(0);
  }

  const int c0 = tid, c1 = tid + 256;      // this thread's two 16B chunks

  // my output cell (row kq of group, col w*64+wv*16+cc); also my xi address
  const size_t ocell = (size_t)(g * RPG + kq) * LL + w * 64 + wv * 16 + cc;

  // ---- prologue: prefetch xi(0) ----
  float xv_next;
  asm volatile("global_load_dword %0, %1, off"
               : "=&v"(xv_next) : "v"(out + ocell) : "memory");

  for (int t = 0; t < TT; ++t) {
    const unsigned ptag = (unsigned)((t >> 1) & 1);        // expected tag
    const unsigned ntag = (unsigned)(((t + 1) >> 1) & 1);  // tag for h_{t+1}

    // ---- poll-gather: re-load own 2 chunks until all 8 tags match ----
    const unsigned short* hcur = hbuf + (size_t)(t & 1) * 65536 + g * 4096;
    const unsigned short* p0 = hcur + c0 * 8;
    const unsigned short* p1 = hcur + c1 * 8;
    u32x4 hv0, hv1;
    {
      int good;
      do {
        asm volatile(
            "global_load_dwordx4 %0, %2, off sc1\n\t"
            "global_load_dwordx4 %1, %3, off sc1\n\t"
            "s_waitcnt vmcnt(0)"
            : "=&v"(hv0), "=&v"(hv1) : "v"(p0), "v"(p1) : "memory");
        good = ((hv0[0] & 1) == ptag) & ((hv0[1] & 1) == ptag) &
               ((hv0[2] & 1) == ptag) & ((hv0[3] & 1) == ptag) &
               ((hv1[0] & 1) == ptag) & ((hv1[1] & 1) == ptag) &
               ((hv1[2] & 1) == ptag) & ((hv1[3] & 1) == ptag);
      } while (__all(good) == 0);
    }
    __builtin_amdgcn_sched_barrier(0);
    unsigned short* hw = hA[t & 1];
    *(u32x4*)(hw + c0 * 8) = hv0;
    *(u32x4*)(hw + c1 * 8) = hv1;
    float xv = xv_next;                    // xi landed under the poll
    __syncthreads();                       // the ONE block barrier per step

    // ---- MFMA: K=1024, A from LDS (broadcast reads), B in VGPRs ----
    f32x4 a0 = {}, a1 = {}, a2 = {}, a3 = {};
#pragma unroll
    for (int ks = 0; ks < 32; ks += 4) {
      bf16x8 A0 = ld_frag(hw + (ks * 16 + kq * 4 + rdup) * 8);
      bf16x8 A1 = ld_frag(hw + ((ks + 1) * 16 + kq * 4 + rdup) * 8);
      bf16x8 A2 = ld_frag(hw + ((ks + 2) * 16 + kq * 4 + rdup) * 8);
      bf16x8 A3 = ld_frag(hw + ((ks + 3) * 16 + kq * 4 + rdup) * 8);
      a0 = __builtin_amdgcn_mfma_f32_16x16x32_bf16(
          A0, __builtin_bit_cast(bf16x8, Breg[ks]), a0, 0, 0, 0);
      a1 = __builtin_amdgcn_mfma_f32_16x16x32_bf16(
          A1, __builtin_bit_cast(bf16x8, Breg[ks + 1]), a1, 0, 0, 0);
      a2 = __builtin_amdgcn_mfma_f32_16x16x32_bf16(
          A2, __builtin_bit_cast(bf16x8, Breg[ks + 2]), a2, 0, 0, 0);
      a3 = __builtin_amdgcn_mfma_f32_16x16x32_bf16(
          A3, __builtin_bit_cast(bf16x8, Breg[ks + 3]), a3, 0, 0, 0);
    }
    f32x4 s = (a0 + a1) + (a2 + a3);

    // ---- all-lane epilogue: lane owns (row kq, col cc) ----
    float hval = tanhf(s[kq] + xv);
    unsigned short hbf = f2bf(hval);
    if ((cc & 1) == 0)                     // even elements carry the tag
      hbf = (unsigned short)((hbf & ~1u) | ntag);
    packb[wv][(cc >> 3) * 32 + kq * 8 + (cc & 7)] = hbf;
    asm volatile("s_waitcnt lgkmcnt(0)" ::: "memory");
    __builtin_amdgcn_sched_barrier(0);

    // ---- publish h (sc1) — no drain, no flag; then out + xi(t+1) ----
    unsigned short* hnext = hbuf + (size_t)((t + 1) & 1) * 65536 + g * 4096;
    if (ln < 8) {
      u32x4 pk = *(const u32x4*)(&packb[wv][ln * 8]);
      unsigned short* dp = hnext + ks_w * 128 + half * 64 + ln * 8;
      asm volatile("global_store_dwordx4 %0, %1, off sc1"
                   :: "v"(dp), "v"(pk) : "memory");
    }
    out[(size_t)t * 65536 + ocell] = hval;
    {
      int tn = (t + 1 < TT) ? (t + 1) : t;
      asm volatile("global_load_dword %0, %1, off"
                   : "=&v"(xv_next) : "v"(out + (size_t)tn * 65536 + ocell)
                   : "memory");
    }
  }
}

extern "C" void kernel_launch(void* const* d_in, const int* in_sizes, int n_in,
                              void* d_out, int out_size, void* d_ws, size_t ws_size,
                              hipStream_t stream) {
  const float* x  = (const float*)d_in[0];
  const float* h0 = (const float*)d_in[1];
  const float* Wi = (const float*)d_in[2];
  const float* bi = (const float*)d_in[3];
  const float* Wh = (const float*)d_in[4];
  float* out = (float*)d_out;
  char* ws = (char*)d_ws;
  unsigned short* wsWi  = (unsigned short*)(ws + WSWI_OFF);
  unsigned short* wsWh2 = (unsigned short*)(ws + WSWH_OFF);
  unsigned short* hbuf  = (unsigned short*)(ws + HBUF_OFF);

  prep_kernel<<<832, 256, 0, stream>>>(h0, Wi, Wh, wsWi, wsWh2, hbuf);
  xi_gemm<<<dim3(8, 256), 256, 0, stream>>>(x, bi, wsWi, out);
  void* args[] = {(void*)&wsWh2, (void*)&out, (void*)&hbuf};
  (void)hipLaunchCooperativeKernel(reinterpret_cast<void*>(scan_kernel),
                                   dim3(NWGS), dim3(256), args, 0, stream);
}